// Round 1
// baseline (734.444 us; speedup 1.0000x reference)
//
#include <hip/hip_runtime.h>
#include <hip/hip_cooperative_groups.h>
#include <math.h>
#include <stdint.h>

namespace cg = cooperative_groups;

#define DI __device__ __forceinline__

typedef __attribute__((ext_vector_type(8))) short bf16x8;
typedef __attribute__((ext_vector_type(4))) float f32x4;
typedef __attribute__((ext_vector_type(4))) int i32x4;

DI float elu_f(float v) { return v > 0.f ? v : expm1f(v); }

DI unsigned short f2bf(float f) {  // fp32 -> bf16 RNE
  uint32_t u = __float_as_uint(f);
  return (unsigned short)((u + 0x7FFFu + ((u >> 16) & 1u)) >> 16);
}

// ---------------- threefry2x32 (JAX, 20 rounds)
DI void threefry2x32(uint32_t k0, uint32_t k1, uint32_t& x0, uint32_t& x1) {
  uint32_t ks0 = k0, ks1 = k1, ks2 = k0 ^ k1 ^ 0x1BD11BDAu;
  x0 += ks0; x1 += ks1;
#define TFR(r) { x0 += x1; x1 = (x1 << r) | (x1 >> (32 - r)); x1 ^= x0; }
  TFR(13) TFR(15) TFR(26) TFR(6)   x0 += ks1; x1 += ks2 + 1u;
  TFR(17) TFR(29) TFR(16) TFR(24)  x0 += ks2; x1 += ks0 + 2u;
  TFR(13) TFR(15) TFR(26) TFR(6)   x0 += ks0; x1 += ks1 + 3u;
  TFR(17) TFR(29) TFR(16) TFR(24)  x0 += ks1; x1 += ks2 + 4u;
  TFR(13) TFR(15) TFR(26) TFR(6)   x0 += ks2; x1 += ks0 + 5u;
#undef TFR
}

DI float erfinv_f(float x) {  // Giles erfinv (rel err ~1e-6 << bf16 quantum)
  float w = -logf((1.0f - x) * (1.0f + x));
  float p;
  if (w < 5.0f) {
    w -= 2.5f;
    p = 2.81022636e-08f;
    p = fmaf(p, w, 3.43273939e-07f);
    p = fmaf(p, w, -3.5233877e-06f);
    p = fmaf(p, w, -4.39150654e-06f);
    p = fmaf(p, w, 0.00021858087f);
    p = fmaf(p, w, -0.00125372503f);
    p = fmaf(p, w, -0.00417768164f);
    p = fmaf(p, w, 0.246640727f);
    p = fmaf(p, w, 1.50140941f);
  } else {
    w = sqrtf(w) - 3.0f;
    p = -0.000200214257f;
    p = fmaf(p, w, 0.000100950558f);
    p = fmaf(p, w, 0.00134934322f);
    p = fmaf(p, w, -0.00367342844f);
    p = fmaf(p, w, 0.00573950773f);
    p = fmaf(p, w, -0.0076224613f);
    p = fmaf(p, w, 0.00943887047f);
    p = fmaf(p, w, 1.00167406f);
    p = fmaf(p, w, 2.83297682f);
  }
  return p * x;
}

struct MegaArgs {
  const float *x, *c;
  const float *fc1w, *fc1b, *fc2w, *fc2b, *muw, *mub, *lvw, *lvb;
  const float *g0w, *g0b, *g1w, *g1b, *g2w, *g2b;
  const float *w0, *b0, *w1, *b1, *w2, *b2;
  unsigned short *Ax, *Axh, *Axh2, *A0, *A1, *A2;
  unsigned short *fc1t, *fc2t, *mlvt, *g0t, *g1t, *w0b, *w1b, *w2b;
  float *cf, *outY, *outMu, *outLv;
};

// =====================================================================
// GEMM job: 32 rows x 32 cols, 128 thr = 2 waves splitting columns.
// Identical math/order to the previous pipe32 kernel; job id replaces
// (blockIdx.x, blockIdx.y) as (job & 63, job >> 6).
template <int KT, int NE, int D, bool ELU, bool OUTF32>
DI void gemm_job(unsigned char* smemv, int job,
                 const unsigned short* __restrict__ A,          // [2048][Kp]
                 const unsigned short* __restrict__ Wt, int N,  // [NE][N][Kp]
                 const float* __restrict__ bias,                // [NE][N]
                 const float* __restrict__ cfp,                 // [2048][8] | null
                 unsigned short* __restrict__ Cb, int ldcb, int cb_off,
                 float* __restrict__ Cf) {
  constexpr int Kp = KT * 32, TT = NE * KT;
  float* bias_s = (float*)smemv;         // NE*32 floats
  float* cfs = bias_s + NE * 32;         // 256 floats (NE>1)
  const int tid = threadIdx.x, lane = tid & 63, wv = tid >> 6;  // wv 0,1
  const int q = lane >> 4, l16 = lane & 15;
  const int bx = job & 63, by = job >> 6;
  const int m0 = bx * 32;
  const int n0 = by * 32 + wv * 16;           // wave-private col slice
  const int gc = n0 + l16;
  const int wrow = (gc < N) ? gc : (N - 1);   // clamp: OOB lanes load junk, never stored
  const unsigned short* wlane = Wt + (size_t)wrow * Kp + q * 8;

  bf16x8 ring[D];
#pragma unroll
  for (int g = 0; g < D; g++) {
    if (g < TT) {
      int e = g / KT, c = g % KT;
      ring[g] = *(const bf16x8*)(wlane + (size_t)e * N * Kp + c * 32);
    }
  }
  bf16x8 areg[2][KT];
#pragma unroll
  for (int t = 0; t < 2; t++) {
    const unsigned short* alane = A + (size_t)(m0 + t * 16 + l16) * Kp + q * 8;
#pragma unroll
    for (int c = 0; c < KT; c++) areg[t][c] = *(const bf16x8*)(alane + c * 32);
  }

  __syncthreads();  // LDS reuse guard (previous job/stage epilogue)
  if (NE == 1) {
    if (tid < 32) {
      int col = by * 32 + tid;
      bias_s[tid] = (col < N) ? bias[col] : 0.f;
    }
  } else {
    for (int idx = tid; idx < NE * 32; idx += 128) {
      int e = idx >> 5, col = by * 32 + (idx & 31);
      bias_s[idx] = (col < N) ? bias[(size_t)e * N + col] : 0.f;
    }
    for (int idx = tid; idx < 256; idx += 128)
      cfs[idx] = cfp[(size_t)(m0 + (idx >> 3)) * 8 + (idx & 7)];
  }
  __syncthreads();

  f32x4 acc[2] = {{0.f, 0.f, 0.f, 0.f}, {0.f, 0.f, 0.f, 0.f}};
  f32x4 accF[2] = {{0.f, 0.f, 0.f, 0.f}, {0.f, 0.f, 0.f, 0.f}};
#pragma unroll
  for (int g = 0; g < TT; g++) {
    const int e = g / KT, c = g % KT;
    bf16x8 bv = ring[g % D];
    acc[0] = __builtin_amdgcn_mfma_f32_16x16x32_bf16(areg[0][c], bv, acc[0], 0, 0, 0);
    acc[1] = __builtin_amdgcn_mfma_f32_16x16x32_bf16(areg[1][c], bv, acc[1], 0, 0, 0);
    if (g + D < TT) {
      int e2 = (g + D) / KT, c2 = (g + D) % KT;
      ring[g % D] = *(const bf16x8*)(wlane + (size_t)e2 * N * Kp + c2 * 32);
    }
    if (NE > 1 && c == KT - 1) {  // expert boundary: exact fp32 fold
      float bv2 = bias_s[e * 32 + wv * 16 + l16];
#pragma unroll
      for (int t = 0; t < 2; t++)
#pragma unroll
        for (int r = 0; r < 4; r++) {
          float ce = cfs[(t * 16 + q * 4 + r) * 8 + e];
          accF[t][r] += ce * (acc[t][r] + bv2);
          acc[t][r] = 0.f;
        }
    }
  }

  if (gc < N) {
#pragma unroll
    for (int t = 0; t < 2; t++)
#pragma unroll
      for (int r = 0; r < 4; r++) {
        int row = m0 + t * 16 + q * 4 + r;
        float v = (NE > 1) ? accF[t][r] : (acc[t][r] + bias_s[wv * 16 + l16]);
        if (ELU) v = elu_f(v);
        if (OUTF32) Cf[(size_t)row * 267 + gc] = v;
        else Cb[(size_t)row * ldcb + cb_off + gc] = f2bf(v);
      }
  }
}

// =====================================================================
// Expert-weight transpose job (64x64 tile, 128 thr). t: 0..159 w0,
// 160..319 w1, 320..519 w2 — same tiling as old k_prep, re-laned.
DI void transpose_job(unsigned char* smemv, int t, const MegaArgs& a) {
  unsigned short (*T)[72] = (unsigned short (*)[72])smemv;
  const int tid = threadIdx.x;
  const float* W; unsigned short* D; int K, N2, Kp2, ldW, e, kt, nt;
  if (t < 160)      { e = t / 20;  int lt = t % 20;  kt = lt / 4; nt = lt % 4; W = a.w0; D = a.w0b; K = 299; N2 = 256; Kp2 = 320; ldW = 256; }
  else if (t < 320) { int u = t - 160; e = u / 20; int lt = u % 20; kt = lt / 4; nt = lt % 4; W = a.w1; D = a.w1b; K = 288; N2 = 256; Kp2 = 288; ldW = 256; }
  else              { int u = t - 320; e = u / 25; int lt = u % 25; kt = lt / 5; nt = lt % 5; W = a.w2; D = a.w2b; K = 288; N2 = 267; Kp2 = 288; ldW = 267; }
  const int k0 = kt * 64, n0 = nt * 64;
  const float* We = W + (size_t)e * K * ldW;
  const int jj = tid & 63, ii0 = tid >> 6;  // ii0 in 0..1
  __syncthreads();  // LDS reuse guard
#pragma unroll
  for (int p = 0; p < 32; p++) {
    int i = ii0 + p * 2;
    int gk = k0 + i, gn = n0 + jj;
    float v = (gk < K && gn < N2) ? We[(size_t)gk * ldW + gn] : 0.f;
    T[jj][i] = f2bf(v);
  }
  __syncthreads();
  const int j0 = tid >> 2, chb = tid & 3;
#pragma unroll
  for (int jh = 0; jh < 2; jh++) {
    int j = j0 + jh * 32;
    int gn = n0 + j;
    if (gn < N2) {
      unsigned short* drow = D + ((size_t)e * N2 + gn) * Kp2 + k0;
#pragma unroll
      for (int s = 0; s < 2; s++) {
        int ch = chb + s * 4;
        if (k0 + ch * 8 < Kp2) {
          i32x4 v = *(i32x4*)(&T[j][ch * 8]);
          *(i32x4*)(drow + ch * 8) = v;
        }
      }
    }
  }
}

// simple fp32->bf16 row conversion (zero-padded to Kp2)
DI void conv_row(const float* src, unsigned short* dst, int Ks, int Kp2) {
  for (int k = threadIdx.x; k < Kp2; k += 128)
    dst[k] = (k < Ks) ? f2bf(src[k]) : (unsigned short)0;
}

// activation prep: 4 rows per block (512 blocks cover 2048 rows)
DI void act_job(int bb, const MegaArgs& a) {
  const int tid = threadIdx.x;
  for (int rr = 0; rr < 4; rr++) {
    int b = bb * 4 + rr;
    const float* xr = a.x + (size_t)b * 267;
    const float* cr = a.c + (size_t)b * 267;
    unsigned short* axr = a.Ax + (size_t)b * 544;
    for (int k = tid; k < 544; k += 128) {
      float v = (k < 267) ? xr[k] : ((k < 534) ? cr[k - 267] : 0.f);
      axr[k] = f2bf(v);
    }
    unsigned short* ahr = a.Axh + (size_t)b * 544;
    unsigned short* ah2 = a.Axh2 + (size_t)b * 544;
    for (int k = tid; k < 267; k += 128) { unsigned short v = f2bf(xr[k]); ahr[k] = v; ah2[k] = v; }
    for (int k = 523 + tid; k < 544; k += 128) { ahr[k] = 0; ah2[k] = 0; }
    unsigned short* a0r = a.A0 + (size_t)b * 320;
    for (int k = tid; k < 288; k += 128)
      a0r[32 + k] = (k < 267) ? f2bf(cr[k]) : (unsigned short)0;
  }
}

// =====================================================================
// mu/lv GEMM + z + full gate stack, re-laned from 256 thr to 128 thr
// (each wave covers 2 col-halves; identical (row,j) threefry mapping).
struct MulvS {
  float mlvS[16 * 65];
  unsigned short A0p[16 * 328];
  unsigned short gaB[16 * 72];
  unsigned short g1B[64 * 72];
  float g2wT[64 * 8];
  float gB[16 * 65];
  float lg[16 * 8];
};

DI void mulv_job(unsigned char* smemv, int blk, const MegaArgs& a) {
  MulvS& S = *(MulvS*)smemv;
  const int tid = threadIdx.x, lane = tid & 63, wv = tid >> 6;
  const int q = lane >> 4, l16 = lane & 15;
  const int m0 = blk * 16;

  const unsigned short* alane = a.Axh2 + (size_t)(m0 + l16) * 544 + q * 8;
  bf16x8 areg[17];
#pragma unroll
  for (int c = 0; c < 17; c++) areg[c] = *(const bf16x8*)(alane + c * 32);
#pragma unroll
  for (int h = 0; h < 2; h++) {
    const int cl = h * 32 + wv * 16 + l16;  // 0..63 over h
    const unsigned short* wlA = a.mlvt + (size_t)cl * 544 + q * 8;
    bf16x8 ring[8];
#pragma unroll
    for (int g = 0; g < 8; g++) ring[g] = *(const bf16x8*)(wlA + g * 32);
    f32x4 acc = {0.f, 0.f, 0.f, 0.f};
#pragma unroll
    for (int g = 0; g < 17; g++) {
      acc = __builtin_amdgcn_mfma_f32_16x16x32_bf16(areg[g], ring[g % 8], acc, 0, 0, 0);
      if (g + 8 < 17) ring[g % 8] = *(const bf16x8*)(wlA + (g + 8) * 32);
    }
#pragma unroll
    for (int r = 0; r < 4; r++) S.mlvS[(q * 4 + r) * 65 + cl] = acc[r];
  }
  for (int idx = tid; idx < 576; idx += 128) {
    int row = idx / 36, ch = 4 + idx % 36;
    *(i32x4*)(S.A0p + row * 328 + ch * 8) =
        *(const i32x4*)(a.A0 + (size_t)(m0 + row) * 320 + ch * 8);
  }
  if (tid < 16) { i32x4 z4 = {0, 0, 0, 0}; *(i32x4*)(S.A0p + tid * 328 + 320) = z4; }
  for (int idx = tid; idx < 512; idx += 128) {
    int row = idx >> 3, ch = idx & 7;
    *(i32x4*)(S.g1B + row * 72 + ch * 8) = *(const i32x4*)(a.g1t + (size_t)row * 64 + ch * 8);
  }
  for (int idx = tid; idx < 512; idx += 128)
    S.g2wT[(idx & 63) * 8 + (idx >> 6)] = a.g2w[idx];
  __syncthreads();

  {
    const int m = tid >> 3, j0 = (tid & 7) * 4, R = m0 + m;
#pragma unroll
    for (int jj = 0; jj < 4; jj++) {
      int j = j0 + jj;
      float mu = S.mlvS[m * 65 + j] + a.mub[j];
      float lvv = S.mlvS[m * 65 + j + 32] + a.lvb[j];
      uint32_t x0 = 0u, x1 = (uint32_t)(R * 32 + j);
      threefry2x32(0u, 42u, x0, x1);
      uint32_t bits = x0 ^ x1;
      float f = __uint_as_float((bits >> 9) | 0x3F800000u) - 1.0f;
      const float lo = -0.99999994039535522461f;
      float u = fmaf(f, 2.0f, lo);
      u = fmaxf(u, lo);
      float eps = 1.41421356237f * erfinv_f(u);
      float z = fmaf(eps, expf(0.5f * lvv), mu);
      a.outMu[(size_t)R * 32 + j] = mu;
      a.outLv[(size_t)R * 32 + j] = lvv;
      unsigned short zb = f2bf(z);
      S.A0p[m * 328 + j] = zb;
      a.A0[(size_t)R * 320 + j] = zb;
      a.A1[(size_t)R * 288 + j] = zb;
      a.A2[(size_t)R * 288 + j] = zb;
    }
  }
  __syncthreads();

#pragma unroll
  for (int h = 0; h < 2; h++) {
    const int cl = h * 32 + wv * 16 + l16;
    const unsigned short* wlC = a.g0t + (size_t)cl * 320 + q * 8;
    bf16x8 ring2[8];
#pragma unroll
    for (int g = 0; g < 8; g++) ring2[g] = *(const bf16x8*)(wlC + g * 32);
    f32x4 accC = {0.f, 0.f, 0.f, 0.f};
#pragma unroll
    for (int g = 0; g < 10; g++) {
      bf16x8 av = *(const bf16x8*)(S.A0p + l16 * 328 + g * 32 + q * 8);
      accC = __builtin_amdgcn_mfma_f32_16x16x32_bf16(av, ring2[g % 8], accC, 0, 0, 0);
      if (g + 8 < 10) ring2[g % 8] = *(const bf16x8*)(wlC + (g + 8) * 32);
    }
    float bc = a.g0b[cl];
#pragma unroll
    for (int r = 0; r < 4; r++)
      S.gaB[(q * 4 + r) * 72 + cl] = f2bf(elu_f(accC[r] + bc));
  }
  __syncthreads();

#pragma unroll
  for (int h = 0; h < 2; h++) {
    const int cl = h * 32 + wv * 16 + l16;
    f32x4 accD = {0.f, 0.f, 0.f, 0.f};
#pragma unroll
    for (int tau = 0; tau < 2; tau++) {
      bf16x8 av = *(const bf16x8*)(S.gaB + l16 * 72 + tau * 32 + q * 8);
      bf16x8 bv = *(const bf16x8*)(S.g1B + cl * 72 + tau * 32 + q * 8);
      accD = __builtin_amdgcn_mfma_f32_16x16x32_bf16(av, bv, accD, 0, 0, 0);
    }
    float bc = a.g1b[cl];
#pragma unroll
    for (int r = 0; r < 4; r++)
      S.gB[(q * 4 + r) * 65 + cl] = elu_f(accD[r] + bc);
  }
  __syncthreads();

  {
    int r = tid >> 3, e = tid & 7;
    float d = a.g2b[e];
#pragma unroll 8
    for (int k = 0; k < 64; k++) d = fmaf(S.gB[r * 65 + k], S.g2wT[k * 8 + e], d);
    S.lg[r * 8 + e] = d;
  }
  __syncthreads();
  if (tid < 16) {
    float mx = S.lg[tid * 8];
#pragma unroll
    for (int e2 = 1; e2 < 8; e2++) mx = fmaxf(mx, S.lg[tid * 8 + e2]);
    float s = 0.f, ex[8];
#pragma unroll
    for (int e2 = 0; e2 < 8; e2++) { ex[e2] = expf(S.lg[tid * 8 + e2] - mx); s += ex[e2]; }
    float inv = 1.f / s;
#pragma unroll
    for (int e2 = 0; e2 < 8; e2++) a.cf[(size_t)(m0 + tid) * 8 + e2] = ex[e2] * inv;
  }
}

// =====================================================================
// THE fused pipeline: 512 blocks x 128 thr, cooperative launch.
// Stage plan (conversions ride in slack so prep leaves the critical path):
//   P0: x/c->bf16 activations + fc1t            | sync
//   S1: fc1 GEMM (512 jobs) + fc2t/mlvt/g0t/g1t | sync
//   S2: fc2 GEMM (512 jobs) + w0 transpose      | sync
//   S3: mulv+gate (128 blks) || w1/w2 transpose | sync
//   S4: L0 (512 jobs) | sync | S5: L1 | sync | S6: L2 (576 jobs, looped)
__global__ __launch_bounds__(128, 2) void mega(MegaArgs a) {
  __shared__ __align__(16) unsigned char smem[sizeof(MulvS)];
  cg::grid_group grid = cg::this_grid();
  const int bid = blockIdx.x;

  // ---- P0
  act_job(bid, a);
  if (bid < 256) conv_row(a.fc1w + (size_t)bid * 534, a.fc1t + (size_t)bid * 544, 534, 544);
  __threadfence();
  grid.sync();

  // ---- S1: fc1 + small-weight conversions
  gemm_job<17, 1, 12, true, false>(smem, bid, a.Ax, a.fc1t, 256, a.fc1b, nullptr,
                                   a.Axh, 544, 267, nullptr);
  if (bid < 256) {
    conv_row(a.fc2w + (size_t)bid * 523, a.fc2t + (size_t)bid * 544, 523, 544);
  } else if (bid < 320) {
    int n = bid - 256;
    const float* s = (n < 32) ? (a.muw + (size_t)n * 523) : (a.lvw + (size_t)(n - 32) * 523);
    conv_row(s, a.mlvt + (size_t)n * 544, 523, 544);
  } else if (bid < 384) {
    int n = bid - 320;
    conv_row(a.g0w + (size_t)n * 299, a.g0t + (size_t)n * 320, 299, 320);
  } else if (bid < 448) {
    int n = bid - 384;
    conv_row(a.g1w + (size_t)n * 64, a.g1t + (size_t)n * 64, 64, 64);
  }
  __threadfence();
  grid.sync();

  // ---- S2: fc2 + w0 transpose
  gemm_job<17, 1, 12, true, false>(smem, bid, a.Axh, a.fc2t, 256, a.fc2b, nullptr,
                                   a.Axh2, 544, 267, nullptr);
  if (bid < 160) transpose_job(smem, bid, a);
  __threadfence();
  grid.sync();

  // ---- S3: mulv+gate on 128 blocks, w1/w2 transpose on the other 360
  if (bid < 128) mulv_job(smem, bid, a);
  else if (bid < 488) transpose_job(smem, 160 + (bid - 128), a);
  __threadfence();
  grid.sync();

  // ---- S4: expert layer 0
  gemm_job<10, 8, 12, true, false>(smem, bid, a.A0, a.w0b, 256, a.b0, a.cf,
                                   a.A1, 288, 32, nullptr);
  __threadfence();
  grid.sync();

  // ---- S5: expert layer 1
  gemm_job<9, 8, 12, true, false>(smem, bid, a.A1, a.w1b, 256, a.b1, a.cf,
                                  a.A2, 288, 32, nullptr);
  __threadfence();
  grid.sync();

  // ---- S6: expert layer 2 (N=267 -> 64x9 = 576 jobs)
  for (int j = bid; j < 576; j += 512)
    gemm_job<9, 8, 12, false, true>(smem, j, a.A2, a.w2b, 267, a.b2, a.cf,
                                    nullptr, 0, 0, a.outY);
}

// =====================================================================
extern "C" void kernel_launch(void* const* d_in, const int* in_sizes, int n_in,
                              void* d_out, int out_size, void* d_ws, size_t ws_size,
                              hipStream_t stream) {
  (void)in_sizes; (void)n_in; (void)out_size; (void)ws_size;
  float* out = (float*)d_out;
  float* ws = (float*)d_ws;

  MegaArgs a;
  a.x    = (const float*)d_in[0];
  a.c    = (const float*)d_in[1];
  a.fc1w = (const float*)d_in[2];  a.fc1b = (const float*)d_in[3];
  a.fc2w = (const float*)d_in[4];  a.fc2b = (const float*)d_in[5];
  a.muw  = (const float*)d_in[6];  a.mub  = (const float*)d_in[7];
  a.lvw  = (const float*)d_in[8];  a.lvb  = (const float*)d_in[9];
  a.g0w  = (const float*)d_in[10]; a.g0b  = (const float*)d_in[11];
  a.g1w  = (const float*)d_in[12]; a.g1b  = (const float*)d_in[13];
  a.g2w  = (const float*)d_in[14]; a.g2b  = (const float*)d_in[15];
  a.w0   = (const float*)d_in[16]; a.b0   = (const float*)d_in[17];
  a.w1   = (const float*)d_in[18]; a.b1   = (const float*)d_in[19];
  a.w2   = (const float*)d_in[20]; a.b2   = (const float*)d_in[21];

  a.outY  = out;
  a.outMu = out + 2048 * 267;
  a.outLv = a.outMu + 2048 * 32;

  a.Ax   = (unsigned short*)(ws);
  a.Axh  = (unsigned short*)(ws + 557056);
  a.Axh2 = (unsigned short*)(ws + 1114112);
  a.A0   = (unsigned short*)(ws + 1671168);
  a.A1   = (unsigned short*)(ws + 1998848);
  a.A2   = (unsigned short*)(ws + 2293760);
  a.fc1t = (unsigned short*)(ws + 2588672);
  a.fc2t = (unsigned short*)(ws + 2658304);
  a.mlvt = (unsigned short*)(ws + 2727936);
  a.g0t  = (unsigned short*)(ws + 2745344);
  a.g1t  = (unsigned short*)(ws + 2755584);
  a.w0b  = (unsigned short*)(ws + 2757632);
  a.w1b  = (unsigned short*)(ws + 3085312);
  a.w2b  = (unsigned short*)(ws + 3380224);
  a.cf   = ws + 3687808;

  void* params[] = {(void*)&a};
  hipLaunchCooperativeKernel((const void*)mega, dim3(512), dim3(128), params, 0, stream);
}

// Round 2
// 213.940 us; speedup vs baseline: 3.4330x; 3.4330x over previous
//
#include <hip/hip_runtime.h>
#include <math.h>
#include <stdint.h>

#define DI __device__ __forceinline__

typedef __attribute__((ext_vector_type(8))) short bf16x8;
typedef __attribute__((ext_vector_type(4))) float f32x4;
typedef __attribute__((ext_vector_type(4))) int i32x4;

#define MFMA16(av, bv, acc) __builtin_amdgcn_mfma_f32_16x16x32_bf16(av, bv, acc, 0, 0, 0)

DI float elu_f(float v) { return v > 0.f ? v : expm1f(v); }

DI unsigned short f2bf(float f) {  // fp32 -> bf16 RNE
  uint32_t u = __float_as_uint(f);
  return (unsigned short)((u + 0x7FFFu + ((u >> 16) & 1u)) >> 16);
}

// ---------------- threefry2x32 (JAX, 20 rounds)
DI void threefry2x32(uint32_t k0, uint32_t k1, uint32_t& x0, uint32_t& x1) {
  uint32_t ks0 = k0, ks1 = k1, ks2 = k0 ^ k1 ^ 0x1BD11BDAu;
  x0 += ks0; x1 += ks1;
#define TFR(r) { x0 += x1; x1 = (x1 << r) | (x1 >> (32 - r)); x1 ^= x0; }
  TFR(13) TFR(15) TFR(26) TFR(6)   x0 += ks1; x1 += ks2 + 1u;
  TFR(17) TFR(29) TFR(16) TFR(24)  x0 += ks2; x1 += ks0 + 2u;
  TFR(13) TFR(15) TFR(26) TFR(6)   x0 += ks0; x1 += ks1 + 3u;
  TFR(17) TFR(29) TFR(16) TFR(24)  x0 += ks1; x1 += ks2 + 4u;
  TFR(13) TFR(15) TFR(26) TFR(6)   x0 += ks2; x1 += ks0 + 5u;
#undef TFR
}

DI float erfinv_f(float x) {  // Giles erfinv (rel err ~1e-6 << bf16 quantum)
  float w = -logf((1.0f - x) * (1.0f + x));
  float p;
  if (w < 5.0f) {
    w -= 2.5f;
    p = 2.81022636e-08f;
    p = fmaf(p, w, 3.43273939e-07f);
    p = fmaf(p, w, -3.5233877e-06f);
    p = fmaf(p, w, -4.39150654e-06f);
    p = fmaf(p, w, 0.00021858087f);
    p = fmaf(p, w, -0.00125372503f);
    p = fmaf(p, w, -0.00417768164f);
    p = fmaf(p, w, 0.246640727f);
    p = fmaf(p, w, 1.50140941f);
  } else {
    w = sqrtf(w) - 3.0f;
    p = -0.000200214257f;
    p = fmaf(p, w, 0.000100950558f);
    p = fmaf(p, w, 0.00134934322f);
    p = fmaf(p, w, -0.00367342844f);
    p = fmaf(p, w, 0.00573950773f);
    p = fmaf(p, w, -0.0076224613f);
    p = fmaf(p, w, 0.00943887047f);
    p = fmaf(p, w, 1.00167406f);
    p = fmaf(p, w, 2.83297682f);
  }
  return p * x;
}

struct MegaArgs {
  const float *x, *c;
  const float *fc1w, *fc1b, *fc2w, *fc2b, *muw, *mub, *lvw, *lvb;
  const float *g0w, *g0b, *g1w, *g1b, *g2w, *g2b;
  const float *w0, *b0, *w1, *b1, *w2, *b2;
  unsigned short *Ax, *Axh, *Axh2, *A0, *A1, *A2;
  unsigned short *fc1t, *fc2t, *mlvt, *g0t, *g1t, *w0b, *w1b, *w2b;
  float *cf, *outY, *outMu, *outLv;
};

// =====================================================================
// prep (one dispatch, 1673 blocks x 256 thr) — round-0 verbatim minus
// the Axh/Axh2/h-zero writes (chain keeps those in LDS now).
__global__ __launch_bounds__(256) void k_prep(MegaArgs a) {
  __shared__ __align__(16) unsigned short T[64][72];
  const int bb = blockIdx.x, tid = threadIdx.x;
  if (bb < 512) {
    for (int rr = 0; rr < 4; rr++) {
      int b = bb * 4 + rr;
      const float* xr = a.x + (size_t)b * 267;
      const float* cr = a.c + (size_t)b * 267;
      unsigned short* axr = a.Ax + (size_t)b * 544;
      for (int k = tid; k < 544; k += 256) {
        float v = (k < 267) ? xr[k] : ((k < 534) ? cr[k - 267] : 0.f);
        axr[k] = f2bf(v);
      }
      unsigned short* a0r = a.A0 + (size_t)b * 320;
      for (int k = tid; k < 288; k += 256)
        a0r[32 + k] = (k < 267) ? f2bf(cr[k]) : (unsigned short)0;
    }
  } else if (bb < 1152) {
    int r = bb - 512;
    const float* src; unsigned short* dst; int Ks, Kp2;
    if (r < 256)      { src = a.fc1w + (size_t)r * 534; dst = a.fc1t + (size_t)r * 544; Ks = 534; Kp2 = 544; }
    else if (r < 512) { int n = r - 256; src = a.fc2w + (size_t)n * 523; dst = a.fc2t + (size_t)n * 544; Ks = 523; Kp2 = 544; }
    else if (r < 576) { int n = r - 512; src = (n < 32) ? (a.muw + (size_t)n * 523) : (a.lvw + (size_t)(n - 32) * 523);
                        dst = a.mlvt + (size_t)n * 544; Ks = 523; Kp2 = 544; }
    else              { int n = r - 576; src = a.g0w + (size_t)n * 299; dst = a.g0t + (size_t)n * 320; Ks = 299; Kp2 = 320; }
    for (int k = tid; k < Kp2; k += 256) dst[k] = (k < Ks) ? f2bf(src[k]) : (unsigned short)0;
  } else if (bb == 1152) {
    for (int k = tid; k < 4096; k += 256) a.g1t[k] = f2bf(a.g1w[k]);
  } else {
    int t = bb - 1153;
    const float* W; unsigned short* D; int K, N2, Kp2, ldW, e, kt, nt;
    if (t < 160)      { e = t / 20;  int lt = t % 20;  kt = lt / 4; nt = lt % 4; W = a.w0; D = a.w0b; K = 299; N2 = 256; Kp2 = 320; ldW = 256; }
    else if (t < 320) { int u = t - 160; e = u / 20; int lt = u % 20; kt = lt / 4; nt = lt % 4; W = a.w1; D = a.w1b; K = 288; N2 = 256; Kp2 = 288; ldW = 256; }
    else              { int u = t - 320; e = u / 25; int lt = u % 25; kt = lt / 5; nt = lt % 5; W = a.w2; D = a.w2b; K = 288; N2 = 267; Kp2 = 288; ldW = 267; }
    const int k0 = kt * 64, n0 = nt * 64;
    const float* We = W + (size_t)e * K * ldW;
    const int jj = tid & 63, ii0 = tid >> 6;
#pragma unroll
    for (int p = 0; p < 16; p++) {
      int i = ii0 + p * 4;
      int gk = k0 + i, gn = n0 + jj;
      float v = (gk < K && gn < N2) ? We[(size_t)gk * ldW + gn] : 0.f;
      T[jj][i] = f2bf(v);
    }
    __syncthreads();
    int j = tid >> 2, chb = tid & 3;
    int gn = n0 + j;
    if (gn < N2) {
      unsigned short* drow = D + ((size_t)e * N2 + gn) * Kp2 + k0;
#pragma unroll
      for (int s = 0; s < 2; s++) {
        int ch = chb + s * 4;
        if (k0 + ch * 8 < Kp2) {
          i32x4 v = *(i32x4*)(&T[j][ch * 8]);
          *(i32x4*)(drow + ch * 8) = v;
        }
      }
    }
  }
}

// =====================================================================
// k_chain: one block owns 16 rows end-to-end. 128 blocks x 512 thr
// (8 waves). Activations live in LDS; weights stream from L2 via
// per-expert register rings (compile-time ring indices). NO cross-block
// communication -> no device-scope fences, only __syncthreads().
__global__ __launch_bounds__(512, 2) void k_chain(MegaArgs a) {
  __shared__ __align__(16) unsigned short sAxh[16][552];  // x | h | 0-pad
  __shared__ __align__(16) unsigned short sA0[16][328];   // z | c | 0-pad
  __shared__ __align__(16) unsigned short sA1[16][296];   // z | h
  __shared__ float sMlv[16][65];
  __shared__ __align__(16) unsigned short sGa[16][72];
  __shared__ float sGb[16][65];
  __shared__ float sG2[512];
  __shared__ float sLg[128];
  __shared__ float sCf[16][8];

  const int tid = threadIdx.x, lane = tid & 63, w = tid >> 6;
  const int q = lane >> 4, l16 = lane & 15;
  const int m0 = blockIdx.x * 16;

  // ---- P0: stage x into sAxh, c into sA0, transpose g2w
  for (int idx = tid; idx < 16 * 34; idx += 512) {
    int row = idx / 34, ch = idx % 34;  // cols 0..271 (267..271 junk, fc1 overwrites)
    *(i32x4*)(&sAxh[row][ch * 8]) =
        *(const i32x4*)(a.Ax + (size_t)(m0 + row) * 544 + ch * 8);
  }
  for (int idx = tid; idx < 16 * 29; idx += 512) sAxh[idx / 29][523 + idx % 29] = 0;
  for (int idx = tid; idx < 16 * 36; idx += 512) {
    int row = idx / 36, ch = idx % 36;  // cols 32..319 of sA0 (c + zeros)
    *(i32x4*)(&sA0[row][32 + ch * 8]) =
        *(const i32x4*)(a.A0 + (size_t)(m0 + row) * 320 + 32 + ch * 8);
  }
  sG2[(tid & 63) * 8 + (tid >> 6)] = a.g2w[tid];
  __syncthreads();

  // ---- P1: fc1 (A from global Ax, W=fc1t; h1 -> sAxh[.][267..522])
  {
    const int n0 = w * 32, c0 = n0 + l16, c1 = n0 + 16 + l16;
    const unsigned short* ap  = a.Ax   + (size_t)(m0 + l16) * 544 + q * 8;
    const unsigned short* wp0 = a.fc1t + (size_t)c0 * 544 + q * 8;
    const unsigned short* wp1 = a.fc1t + (size_t)c1 * 544 + q * 8;
    bf16x8 r0[8], r1[8], ra[4];
#pragma unroll
    for (int i = 0; i < 8; i++) { r0[i] = *(const bf16x8*)(wp0 + i * 32); r1[i] = *(const bf16x8*)(wp1 + i * 32); }
#pragma unroll
    for (int i = 0; i < 4; i++) ra[i] = *(const bf16x8*)(ap + i * 32);
    f32x4 acc0 = {0.f, 0.f, 0.f, 0.f}, acc1 = {0.f, 0.f, 0.f, 0.f};
#pragma unroll
    for (int c = 0; c < 17; c++) {
      bf16x8 av = ra[c & 3];
      acc0 = MFMA16(av, r0[c & 7], acc0);
      acc1 = MFMA16(av, r1[c & 7], acc1);
      if (c + 4 < 17) ra[c & 3] = *(const bf16x8*)(ap + (c + 4) * 32);
      if (c + 8 < 17) { r0[c & 7] = *(const bf16x8*)(wp0 + (c + 8) * 32);
                        r1[c & 7] = *(const bf16x8*)(wp1 + (c + 8) * 32); }
    }
    float b0v = a.fc1b[c0], b1v = a.fc1b[c1];
#pragma unroll
    for (int r = 0; r < 4; r++) {
      int row = q * 4 + r;
      sAxh[row][267 + c0] = f2bf(elu_f(acc0[r] + b0v));
      sAxh[row][267 + c1] = f2bf(elu_f(acc1[r] + b1v));
    }
  }
  __syncthreads();

  // ---- P2: fc2 (A from sAxh, in-place h2 after barrier)
  {
    const int n0 = w * 32, c0 = n0 + l16, c1 = n0 + 16 + l16;
    const unsigned short* wp0 = a.fc2t + (size_t)c0 * 544 + q * 8;
    const unsigned short* wp1 = a.fc2t + (size_t)c1 * 544 + q * 8;
    bf16x8 r0[8], r1[8];
#pragma unroll
    for (int i = 0; i < 8; i++) { r0[i] = *(const bf16x8*)(wp0 + i * 32); r1[i] = *(const bf16x8*)(wp1 + i * 32); }
    f32x4 acc0 = {0.f, 0.f, 0.f, 0.f}, acc1 = {0.f, 0.f, 0.f, 0.f};
#pragma unroll
    for (int c = 0; c < 17; c++) {
      bf16x8 av = *(const bf16x8*)(&sAxh[l16][c * 32 + q * 8]);
      acc0 = MFMA16(av, r0[c & 7], acc0);
      acc1 = MFMA16(av, r1[c & 7], acc1);
      if (c + 8 < 17) { r0[c & 7] = *(const bf16x8*)(wp0 + (c + 8) * 32);
                        r1[c & 7] = *(const bf16x8*)(wp1 + (c + 8) * 32); }
    }
    __syncthreads();  // all h1 reads done before overwrite
    float b0v = a.fc2b[c0], b1v = a.fc2b[c1];
#pragma unroll
    for (int r = 0; r < 4; r++) {
      int row = q * 4 + r;
      sAxh[row][267 + c0] = f2bf(elu_f(acc0[r] + b0v));
      sAxh[row][267 + c1] = f2bf(elu_f(acc1[r] + b1v));
    }
  }
  __syncthreads();

  // ---- P3: mu/lv GEMM (waves 0..3, 64 cols)
  if (w < 4) {
    const int cl = w * 16 + l16;
    const unsigned short* wp = a.mlvt + (size_t)cl * 544 + q * 8;
    bf16x8 rw[8];
#pragma unroll
    for (int i = 0; i < 8; i++) rw[i] = *(const bf16x8*)(wp + i * 32);
    f32x4 acc = {0.f, 0.f, 0.f, 0.f};
#pragma unroll
    for (int c = 0; c < 17; c++) {
      bf16x8 av = *(const bf16x8*)(&sAxh[l16][c * 32 + q * 8]);
      acc = MFMA16(av, rw[c & 7], acc);
      if (c + 8 < 17) rw[c & 7] = *(const bf16x8*)(wp + (c + 8) * 32);
    }
#pragma unroll
    for (int r = 0; r < 4; r++) sMlv[q * 4 + r][cl] = acc[r];
  }
  __syncthreads();

  // ---- P4: z / RNG (identical mapping to the verified 128-thr version)
  if (tid < 128) {
    const int m = tid >> 3, j0 = (tid & 7) * 4, R = m0 + m;
#pragma unroll
    for (int jj = 0; jj < 4; jj++) {
      int j = j0 + jj;
      float mu = sMlv[m][j] + a.mub[j];
      float lvv = sMlv[m][j + 32] + a.lvb[j];
      uint32_t x0 = 0u, x1 = (uint32_t)(R * 32 + j);
      threefry2x32(0u, 42u, x0, x1);
      uint32_t bits = x0 ^ x1;
      float f = __uint_as_float((bits >> 9) | 0x3F800000u) - 1.0f;
      const float lo = -0.99999994039535522461f;
      float u = fmaf(f, 2.0f, lo);
      u = fmaxf(u, lo);
      float eps = 1.41421356237f * erfinv_f(u);
      float z = fmaf(eps, expf(0.5f * lvv), mu);
      a.outMu[(size_t)R * 32 + j] = mu;
      a.outLv[(size_t)R * 32 + j] = lvv;
      unsigned short zb = f2bf(z);
      sA0[m][j] = zb;
      sA1[m][j] = zb;
    }
  }
  __syncthreads();

  // ---- P5: gate layer0 (waves 0..3; K=320 from sA0)
  if (w < 4) {
    const int cl = w * 16 + l16;
    const unsigned short* wp = a.g0t + (size_t)cl * 320 + q * 8;
    bf16x8 rw[8];
#pragma unroll
    for (int i = 0; i < 8; i++) rw[i] = *(const bf16x8*)(wp + i * 32);
    f32x4 acc = {0.f, 0.f, 0.f, 0.f};
#pragma unroll
    for (int c = 0; c < 10; c++) {
      bf16x8 av = *(const bf16x8*)(&sA0[l16][c * 32 + q * 8]);
      acc = MFMA16(av, rw[c & 7], acc);
      if (c + 8 < 10) rw[c & 7] = *(const bf16x8*)(wp + (c + 8) * 32);
    }
    float bc = a.g0b[cl];
#pragma unroll
    for (int r = 0; r < 4; r++) sGa[q * 4 + r][cl] = f2bf(elu_f(acc[r] + bc));
  }
  __syncthreads();

  // ---- P6: gate layer1 + logits + softmax
  if (w < 4) {
    const int cl = w * 16 + l16;
    bf16x8 bv0 = *(const bf16x8*)(a.g1t + (size_t)cl * 64 + q * 8);
    bf16x8 bv1 = *(const bf16x8*)(a.g1t + (size_t)cl * 64 + 32 + q * 8);
    bf16x8 av0 = *(const bf16x8*)(&sGa[l16][q * 8]);
    bf16x8 av1 = *(const bf16x8*)(&sGa[l16][32 + q * 8]);
    f32x4 acc = {0.f, 0.f, 0.f, 0.f};
    acc = MFMA16(av0, bv0, acc);
    acc = MFMA16(av1, bv1, acc);
    float bc = a.g1b[cl];
#pragma unroll
    for (int r = 0; r < 4; r++) sGb[q * 4 + r][cl] = elu_f(acc[r] + bc);
  }
  __syncthreads();
  if (tid < 128) {
    int r = tid >> 3, e = tid & 7;
    float d = a.g2b[e];
#pragma unroll 8
    for (int k = 0; k < 64; k++) d = fmaf(sGb[r][k], sG2[k * 8 + e], d);
    sLg[r * 8 + e] = d;
  }
  __syncthreads();
  if (tid < 16) {
    float mx = sLg[tid * 8];
#pragma unroll
    for (int e2 = 1; e2 < 8; e2++) mx = fmaxf(mx, sLg[tid * 8 + e2]);
    float s = 0.f, ex[8];
#pragma unroll
    for (int e2 = 0; e2 < 8; e2++) { ex[e2] = expf(sLg[tid * 8 + e2] - mx); s += ex[e2]; }
    float inv = 1.f / s;
#pragma unroll
    for (int e2 = 0; e2 < 8; e2++) sCf[tid][e2] = ex[e2] * inv;
  }
  __syncthreads();

  // ---- P7: expert layer 0 (K=320 from sA0, 8 experts, cf fold)
  {
    const int n0 = w * 32, c0 = n0 + l16, c1 = n0 + 16 + l16;
    const unsigned short* wp0 = a.w0b + (size_t)c0 * 320 + q * 8;
    const unsigned short* wp1 = a.w0b + (size_t)c1 * 320 + q * 8;
    bf16x8 r0[10], r1[10];
#pragma unroll
    for (int c = 0; c < 10; c++) { r0[c] = *(const bf16x8*)(wp0 + c * 32); r1[c] = *(const bf16x8*)(wp1 + c * 32); }
    f32x4 accF0 = {0.f, 0.f, 0.f, 0.f}, accF1 = {0.f, 0.f, 0.f, 0.f};
    for (int e = 0; e < 8; e++) {
      const unsigned short* nx0 = wp0 + (size_t)(e + 1) * 81920;
      const unsigned short* nx1 = wp1 + (size_t)(e + 1) * 81920;
      f32x4 acc0 = {0.f, 0.f, 0.f, 0.f}, acc1 = {0.f, 0.f, 0.f, 0.f};
#pragma unroll
      for (int c = 0; c < 10; c++) {
        bf16x8 av = *(const bf16x8*)(&sA0[l16][c * 32 + q * 8]);
        acc0 = MFMA16(av, r0[c], acc0);
        acc1 = MFMA16(av, r1[c], acc1);
        if (e < 7) { r0[c] = *(const bf16x8*)(nx0 + c * 32); r1[c] = *(const bf16x8*)(nx1 + c * 32); }
      }
      float bv0 = a.b0[e * 256 + c0], bv1 = a.b0[e * 256 + c1];
#pragma unroll
      for (int r = 0; r < 4; r++) {
        float ce = sCf[q * 4 + r][e];
        accF0[r] += ce * (acc0[r] + bv0);
        accF1[r] += ce * (acc1[r] + bv1);
      }
    }
    __syncthreads();  // sA0 reads done (harmless extra guard before sA1 writes)
#pragma unroll
    for (int r = 0; r < 4; r++) {
      int row = q * 4 + r;
      sA1[row][32 + c0] = f2bf(elu_f(accF0[r]));
      sA1[row][32 + c1] = f2bf(elu_f(accF1[r]));
    }
  }
  __syncthreads();

  // ---- P8: expert layer 1 (K=288 from sA1, in-place h after barrier)
  {
    const int n0 = w * 32, c0 = n0 + l16, c1 = n0 + 16 + l16;
    const unsigned short* wp0 = a.w1b + (size_t)c0 * 288 + q * 8;
    const unsigned short* wp1 = a.w1b + (size_t)c1 * 288 + q * 8;
    bf16x8 r0[9], r1[9];
#pragma unroll
    for (int c = 0; c < 9; c++) { r0[c] = *(const bf16x8*)(wp0 + c * 32); r1[c] = *(const bf16x8*)(wp1 + c * 32); }
    f32x4 accF0 = {0.f, 0.f, 0.f, 0.f}, accF1 = {0.f, 0.f, 0.f, 0.f};
    for (int e = 0; e < 8; e++) {
      const unsigned short* nx0 = wp0 + (size_t)(e + 1) * 73728;
      const unsigned short* nx1 = wp1 + (size_t)(e + 1) * 73728;
      f32x4 acc0 = {0.f, 0.f, 0.f, 0.f}, acc1 = {0.f, 0.f, 0.f, 0.f};
#pragma unroll
      for (int c = 0; c < 9; c++) {
        bf16x8 av = *(const bf16x8*)(&sA1[l16][c * 32 + q * 8]);
        acc0 = MFMA16(av, r0[c], acc0);
        acc1 = MFMA16(av, r1[c], acc1);
        if (e < 7) { r0[c] = *(const bf16x8*)(nx0 + c * 32); r1[c] = *(const bf16x8*)(nx1 + c * 32); }
      }
      float bv0 = a.b1[e * 256 + c0], bv1 = a.b1[e * 256 + c1];
#pragma unroll
      for (int r = 0; r < 4; r++) {
        float ce = sCf[q * 4 + r][e];
        accF0[r] += ce * (acc0[r] + bv0);
        accF1[r] += ce * (acc1[r] + bv1);
      }
    }
    __syncthreads();  // all sA1 reads done before overwrite
#pragma unroll
    for (int r = 0; r < 4; r++) {
      int row = q * 4 + r;
      sA1[row][32 + c0] = f2bf(elu_f(accF0[r]));
      sA1[row][32 + c1] = f2bf(elu_f(accF1[r]));
    }
  }
  __syncthreads();

  // ---- P9: expert layer 2 (N=267 -> 17 n-tiles over 8 waves)
  for (int j = w; j < 17; j += 8) {
    const int col = j * 16 + l16;
    const int vcol = (col < 267) ? col : 266;  // clamp; OOB never stored
    const unsigned short* wp = a.w2b + (size_t)vcol * 288 + q * 8;
    bf16x8 rw[9];
#pragma unroll
    for (int c = 0; c < 9; c++) rw[c] = *(const bf16x8*)(wp + c * 32);
    f32x4 accF = {0.f, 0.f, 0.f, 0.f};
    for (int e = 0; e < 8; e++) {
      const unsigned short* nx = wp + (size_t)(e + 1) * 76896;
      f32x4 acc = {0.f, 0.f, 0.f, 0.f};
#pragma unroll
      for (int c = 0; c < 9; c++) {
        bf16x8 av = *(const bf16x8*)(&sA1[l16][c * 32 + q * 8]);
        acc = MFMA16(av, rw[c], acc);
        if (e < 7) rw[c] = *(const bf16x8*)(nx + c * 32);
      }
      float bv = a.b2[e * 267 + vcol];
#pragma unroll
      for (int r = 0; r < 4; r++) {
        float ce = sCf[q * 4 + r][e];
        accF[r] += ce * (acc[r] + bv);
      }
    }
    if (col < 267) {
#pragma unroll
      for (int r = 0; r < 4; r++)
        a.outY[(size_t)(m0 + q * 4 + r) * 267 + col] = accF[r];
    }
  }
}

// =====================================================================
extern "C" void kernel_launch(void* const* d_in, const int* in_sizes, int n_in,
                              void* d_out, int out_size, void* d_ws, size_t ws_size,
                              hipStream_t stream) {
  (void)in_sizes; (void)n_in; (void)out_size; (void)ws_size;
  float* out = (float*)d_out;
  float* ws = (float*)d_ws;

  MegaArgs a;
  a.x    = (const float*)d_in[0];
  a.c    = (const float*)d_in[1];
  a.fc1w = (const float*)d_in[2];  a.fc1b = (const float*)d_in[3];
  a.fc2w = (const float*)d_in[4];  a.fc2b = (const float*)d_in[5];
  a.muw  = (const float*)d_in[6];  a.mub  = (const float*)d_in[7];
  a.lvw  = (const float*)d_in[8];  a.lvb  = (const float*)d_in[9];
  a.g0w  = (const float*)d_in[10]; a.g0b  = (const float*)d_in[11];
  a.g1w  = (const float*)d_in[12]; a.g1b  = (const float*)d_in[13];
  a.g2w  = (const float*)d_in[14]; a.g2b  = (const float*)d_in[15];
  a.w0   = (const float*)d_in[16]; a.b0   = (const float*)d_in[17];
  a.w1   = (const float*)d_in[18]; a.b1   = (const float*)d_in[19];
  a.w2   = (const float*)d_in[20]; a.b2   = (const float*)d_in[21];

  a.outY  = out;
  a.outMu = out + 2048 * 267;
  a.outLv = a.outMu + 2048 * 32;

  a.Ax   = (unsigned short*)(ws);
  a.Axh  = (unsigned short*)(ws + 557056);
  a.Axh2 = (unsigned short*)(ws + 1114112);
  a.A0   = (unsigned short*)(ws + 1671168);
  a.A1   = (unsigned short*)(ws + 1998848);
  a.A2   = (unsigned short*)(ws + 2293760);
  a.fc1t = (unsigned short*)(ws + 2588672);
  a.fc2t = (unsigned short*)(ws + 2658304);
  a.mlvt = (unsigned short*)(ws + 2727936);
  a.g0t  = (unsigned short*)(ws + 2745344);
  a.g1t  = (unsigned short*)(ws + 2755584);
  a.w0b  = (unsigned short*)(ws + 2757632);
  a.w1b  = (unsigned short*)(ws + 3085312);
  a.w2b  = (unsigned short*)(ws + 3380224);
  a.cf   = ws + 3687808;

  k_prep<<<1673, 256, 0, stream>>>(a);
  k_chain<<<128, 512, 0, stream>>>(a);
}